// Round 5
// baseline (15769.693 us; speedup 1.0000x reference)
//
#include <hip/hip_runtime.h>
#include <stdint.h>

// Problem constants (fixed by reference): B=32, T=512, d=1024, Kcb=256
#define NB    32
#define NT    512
#define ND    1024
#define NG    3072      // 3*d
#define NROW  16384     // B*T
#define KCB   256
#define GRU_BLOCKS 128

typedef float  f32x4 __attribute__((ext_vector_type(4)));
typedef short  s16x8 __attribute__((ext_vector_type(8)));

// ---------------- bf16 helpers (hi/lo split precision) ----------------
__device__ __forceinline__ unsigned short f32_to_bf16(float x) {
    union { float f; unsigned int u; } v; v.f = x;
    unsigned int u = v.u;
    return (unsigned short)((u + 0x7FFFu + ((u >> 16) & 1u)) >> 16);
}
__device__ __forceinline__ float bf16_to_f32(unsigned short h) {
    union { float f; unsigned int u; } v; v.u = ((unsigned int)h) << 16; return v.f;
}

// ---------------- W_hh -> bf16 hi/lo split (once per launch) ----------------
__global__ __launch_bounds__(256) void prep_w(const float* __restrict__ W,
                                              unsigned short* __restrict__ Whi,
                                              unsigned short* __restrict__ Wlo) {
    int i = blockIdx.x * 256 + threadIdx.x;   // grid sized exactly: 3072*1024/256
    float w = W[i];
    unsigned short hi = f32_to_bf16(w);
    float rem = w - bf16_to_f32(hi);
    Whi[i] = hi;
    Wlo[i] = f32_to_bf16(rem);
}

// ---------------- quantize: fp64 scores, argmin, copy row, SSD ----------------
__global__ __launch_bounds__(256) void quantize_kernel(
    const float* __restrict__ feat, const float* __restrict__ cb,
    float* __restrict__ out_q, float* __restrict__ out_idx,
    int* __restrict__ idxi, float* __restrict__ acc)
{
    __shared__ float  fr[8][1024];     // 32 KB
    __shared__ double wsco[4];
    __shared__ int    wid[4];
    __shared__ int    winner;
    __shared__ float  sp[4];

    int tid = threadIdx.x;
    int r0  = blockIdx.x * 8;

    for (int i = 0; i < 8; ++i) {
        int g   = i * 256 + tid;
        int row = g >> 8;
        int kq  = g & 255;
        float4 v = ((const float4*)(feat + (long)(r0 + row) * ND))[kq];
        ((float4*)&fr[row][0])[kq] = v;
    }
    __syncthreads();

    double dot[8];
    #pragma unroll
    for (int r = 0; r < 8; ++r) dot[r] = 0.0;
    double cc = 0.0;
    const float4* cbrow = (const float4*)(cb + (long)tid * ND);
    for (int k4 = 0; k4 < 256; ++k4) {
        float4 c = cbrow[k4];
        cc += (double)c.x * (double)c.x + (double)c.y * (double)c.y
            + (double)c.z * (double)c.z + (double)c.w * (double)c.w;
        #pragma unroll
        for (int r = 0; r < 8; ++r) {
            float4 f = ((const float4*)&fr[r][0])[k4];
            dot[r] += (double)(f.x * c.x) + (double)(f.y * c.y)
                    + (double)(f.z * c.z) + (double)(f.w * c.w);
        }
    }

    float ssd_thread = 0.f;
    for (int r = 0; r < 8; ++r) {
        double s = cc - 2.0 * dot[r];
        int idx = tid;
        #pragma unroll
        for (int m = 1; m < 64; m <<= 1) {
            double s2 = __shfl_xor(s, m, 64);
            int    i2 = __shfl_xor(idx, m, 64);
            if (s2 < s || (s2 == s && i2 < idx)) { s = s2; idx = i2; }
        }
        int w = tid >> 6;
        if ((tid & 63) == 0) { wsco[w] = s; wid[w] = idx; }
        __syncthreads();
        if (tid == 0) {
            double bs = wsco[0]; int bi = wid[0];
            for (int w2 = 1; w2 < 4; ++w2)
                if (wsco[w2] < bs || (wsco[w2] == bs && wid[w2] < bi)) { bs = wsco[w2]; bi = wid[w2]; }
            winner = bi;
            out_idx[r0 + r] = (float)bi;
            idxi[r0 + r]    = bi;
        }
        __syncthreads();
        int win = winner;
        float4 q = ((const float4*)(cb + (long)win * ND))[tid];
        ((float4*)(out_q + (long)(r0 + r) * ND))[tid] = q;
        float4 f = ((const float4*)&fr[r][0])[tid];
        float dx = f.x - q.x, dy = f.y - q.y, dz = f.z - q.z, dw = f.w - q.w;
        ssd_thread += dx * dx + dy * dy + dz * dz + dw * dw;
        __syncthreads();
    }

    #pragma unroll
    for (int m = 1; m < 64; m <<= 1) ssd_thread += __shfl_xor(ssd_thread, m, 64);
    if ((tid & 63) == 0) sp[tid >> 6] = ssd_thread;
    __syncthreads();
    if (tid == 0) atomicAdd(&acc[33], sp[0] + sp[1] + sp[2] + sp[3]);
}

// ---------------- fp32 tiled GEMM: C[M,N] = A[M,K] * W[N,K]^T + bias[N] ----------------
__global__ __launch_bounds__(256) void gemm_nt(
    const float* __restrict__ A, const float* __restrict__ W,
    const float* __restrict__ bias, float* __restrict__ C, int N, int K)
{
    __shared__ float As[16][132];
    __shared__ float Bs[16][132];
    int tid = threadIdx.x;
    int m0 = blockIdx.y * 128;
    int n0 = blockIdx.x * 128;
    int tx = tid & 15, ty = tid >> 4;

    float accum[8][8];
    #pragma unroll
    for (int i = 0; i < 8; ++i)
        #pragma unroll
        for (int j = 0; j < 8; ++j) accum[i][j] = 0.f;

    for (int k0 = 0; k0 < K; k0 += 16) {
        #pragma unroll
        for (int i = 0; i < 2; ++i) {
            int f   = tid + i * 256;
            int row = f >> 2;
            int kq  = f & 3;
            float4 a = *(const float4*)(A + (long)(m0 + row) * K + k0 + kq * 4);
            As[kq * 4 + 0][row] = a.x; As[kq * 4 + 1][row] = a.y;
            As[kq * 4 + 2][row] = a.z; As[kq * 4 + 3][row] = a.w;
            float4 b = *(const float4*)(W + (long)(n0 + row) * K + k0 + kq * 4);
            Bs[kq * 4 + 0][row] = b.x; Bs[kq * 4 + 1][row] = b.y;
            Bs[kq * 4 + 2][row] = b.z; Bs[kq * 4 + 3][row] = b.w;
        }
        __syncthreads();
        #pragma unroll
        for (int kk = 0; kk < 16; ++kk) {
            float4 a01 = *(const float4*)&As[kk][ty * 8];
            float4 a23 = *(const float4*)&As[kk][ty * 8 + 4];
            float4 b01 = *(const float4*)&Bs[kk][tx * 8];
            float4 b23 = *(const float4*)&Bs[kk][tx * 8 + 4];
            float av[8] = {a01.x, a01.y, a01.z, a01.w, a23.x, a23.y, a23.z, a23.w};
            float bv[8] = {b01.x, b01.y, b01.z, b01.w, b23.x, b23.y, b23.z, b23.w};
            #pragma unroll
            for (int i = 0; i < 8; ++i)
                #pragma unroll
                for (int j = 0; j < 8; ++j) accum[i][j] += av[i] * bv[j];
        }
        __syncthreads();
    }
    #pragma unroll
    for (int i = 0; i < 8; ++i) {
        float* crow = C + (long)(m0 + ty * 8 + i) * N + n0 + tx * 8;
        const float* brow = bias + n0 + tx * 8;
        float4 o0, o1;
        o0.x = accum[i][0] + brow[0]; o0.y = accum[i][1] + brow[1];
        o0.z = accum[i][2] + brow[2]; o0.w = accum[i][3] + brow[3];
        o1.x = accum[i][4] + brow[4]; o1.y = accum[i][5] + brow[5];
        o1.z = accum[i][6] + brow[6]; o1.w = accum[i][7] + brow[7];
        *(float4*)(crow)     = o0;
        *(float4*)(crow + 4) = o1;
    }
}

// ---------------- persistent GRU v2 (fixed W-hi staging count) ----------------
// 128 blocks x 256 thr (4 waves), each block owns 8 j-cols.
// W-hi slice pinned in LDS (fragment layout), W-lo slice pinned in VGPRs:
// zero per-step W traffic, immune to the barrier's L2-invalidating fences.
// h handed between steps in MFMA A-fragment layout (hA), coalesced wave-loads.
__device__ __forceinline__ void grid_barrier(int* bar, int step) {
    __threadfence();                         // release: write back this XCD's L2
    __syncthreads();                         // (each wave drained vmcnt here)
    if (threadIdx.x == 0) {
        int target = GRU_BLOCKS * (step + 1);
        __hip_atomic_fetch_add(bar, 1, __ATOMIC_ACQ_REL, __HIP_MEMORY_SCOPE_AGENT);
        while (__hip_atomic_load(bar, __ATOMIC_ACQUIRE, __HIP_MEMORY_SCOPE_AGENT) < target)
            __builtin_amdgcn_s_sleep(2);
    }
    __syncthreads();
    __threadfence();                         // acquire: invalidate stale L1/L2
}

__global__ __launch_bounds__(256) void gru_persist(
    float* hs,
    const unsigned short* __restrict__ Whi, const unsigned short* __restrict__ Wlo,
    const float* __restrict__ GIcb, const int* __restrict__ idxi,
    const float* __restrict__ b_hh,
    unsigned short* hA,     // [2 buf][hi/lo][32 kk][2 mt][64 lane][8] ushorts
    int* bar)
{
    __shared__ unsigned short whi[3][32][8][32];   // 48 KB: W-hi in B-frag layout
    __shared__ float red[4][32][25];               // 12.8 KB: k-split partials (valid n<8)

    int tid  = threadIdx.x;
    int lane = tid & 63;
    int w    = tid >> 6;
    int jb   = blockIdx.x * 8;
    int n    = lane & 15, q = lane >> 4;
    int n7   = n & 7;

    // ---- stage W-hi slice into LDS, once (fragment layout [g][kk][r][32]) ----
    // 24 rows x 1024 k = 3072 ushort8 loads; 256 threads -> 12 iterations.
    // (R4 bug: ran only 3 iterations, leaving 3/4 of the tile uninitialized -> NaN.)
    for (int it = 0; it < 12; ++it) {
        int u8 = it * 256 + tid;
        int e  = u8 * 8;
        int r24 = e >> 10;                // 0..23
        int k   = e & 1023;
        int g = r24 >> 3, r = r24 & 7;
        s16x8 v = *(const s16x8*)(Whi + (long)((g << 10) + jb + r) * 1024 + k);
        *(s16x8*)&whi[g][k >> 5][r][k & 31] = v;
    }

    // ---- pin W-lo fragments in VGPRs (wave w covers k in [w*256, w*256+256)) ----
    s16x8 wlof[8][3];
    #pragma unroll
    for (int kl = 0; kl < 8; ++kl)
        #pragma unroll
        for (int g = 0; g < 3; ++g) {
            int kg = w * 256 + kl * 32 + q * 8;
            wlof[kl][g] = *(const s16x8*)(Wlo + (long)((g << 10) + jb + n7) * 1024 + kg);
        }
    __syncthreads();

    // ---- epilogue constants: thread -> one output (b=eb, col jg) ----
    int eb  = tid >> 3;                    // batch 0..31
    int ejl = tid & 7;                     // j-local 0..7
    int jg  = jb + ejl;
    int emt = eb >> 4, erow = eb & 15;
    int eq  = erow >> 2, eer = erow & 3;
    int esidx = eq * 8 + ejl;
    float bhr = b_hh[jg], bhz = b_hh[ND + jg], bhn = b_hh[2 * ND + jg];
    int akk = jg >> 5, aq = (jg >> 3) & 3, aj8 = jg & 7;
    int alane = aq * 16 + (eb & 15);
    int awoff = ((akk * 2 + emt) * 64 + alane) * 8 + aj8;
    float hp = 0.f;                        // h_prev carried in-register

    #pragma unroll 1
    for (int t = 0; t < NT; ++t) {
        const unsigned short* rhi = hA + (((t & 1) * 2 + 0) << 15);
        const unsigned short* rlo = hA + (((t & 1) * 2 + 1) << 15);
        unsigned short* whg = hA + ((((t + 1) & 1) * 2 + 0) << 15);
        unsigned short* wlg = hA + ((((t + 1) & 1) * 2 + 1) << 15);

        f32x4 acc[2][3];
        #pragma unroll
        for (int mt = 0; mt < 2; ++mt)
            #pragma unroll
            for (int g = 0; g < 3; ++g) acc[mt][g] = (f32x4){0.f, 0.f, 0.f, 0.f};

        #pragma unroll
        for (int kl = 0; kl < 8; ++kl) {
            int kk = w * 8 + kl;
            int fo = (kk * 2 * 64 + lane) * 8;
            s16x8 ah0 = *(const s16x8*)(rhi + fo);          // mt=0, coalesced 1KB/wave
            s16x8 al0 = *(const s16x8*)(rlo + fo);
            s16x8 ah1 = *(const s16x8*)(rhi + fo + 512);    // mt=1
            s16x8 al1 = *(const s16x8*)(rlo + fo + 512);
            #pragma unroll
            for (int g = 0; g < 3; ++g) {
                s16x8 bh = *(const s16x8*)&whi[g][kk][n7][q * 8];
                s16x8 bl = wlof[kl][g];
                acc[0][g] = __builtin_amdgcn_mfma_f32_16x16x32_bf16(ah0, bh, acc[0][g], 0, 0, 0);
                acc[0][g] = __builtin_amdgcn_mfma_f32_16x16x32_bf16(al0, bh, acc[0][g], 0, 0, 0);
                acc[0][g] = __builtin_amdgcn_mfma_f32_16x16x32_bf16(ah0, bl, acc[0][g], 0, 0, 0);
                acc[1][g] = __builtin_amdgcn_mfma_f32_16x16x32_bf16(ah1, bh, acc[1][g], 0, 0, 0);
                acc[1][g] = __builtin_amdgcn_mfma_f32_16x16x32_bf16(al1, bh, acc[1][g], 0, 0, 0);
                acc[1][g] = __builtin_amdgcn_mfma_f32_16x16x32_bf16(ah1, bl, acc[1][g], 0, 0, 0);
            }
        }

        // k-split partials (only valid j lanes, n<8)
        if (n < 8) {
            int sidx = q * 8 + n;
            #pragma unroll
            for (int mt = 0; mt < 2; ++mt)
                #pragma unroll
                for (int g = 0; g < 3; ++g)
                    #pragma unroll
                    for (int r = 0; r < 4; ++r)
                        red[w][sidx][(mt * 3 + g) * 4 + r] = acc[mt][g][r];
        }
        __syncthreads();

        // epilogue: 1 output per thread
        float g0 = 0.f, g1 = 0.f, g2 = 0.f;
        #pragma unroll
        for (int ww = 0; ww < 4; ++ww) {
            g0 += red[ww][esidx][(emt * 3 + 0) * 4 + eer];
            g1 += red[ww][esidx][(emt * 3 + 1) * 4 + eer];
            g2 += red[ww][esidx][(emt * 3 + 2) * 4 + eer];
        }
        int cidx = idxi[eb * NT + t];
        const float* gib = GIcb + (long)cidx * NG;
        float xr = gib[jg]      + g0 + bhr;
        float xz = gib[ND + jg] + g1 + bhz;
        float rg = 1.f / (1.f + __expf(-xr));
        float zg = 1.f / (1.f + __expf(-xz));
        float narg = gib[2 * ND + jg] + rg * (g2 + bhn);
        float e2 = __expf(2.f * narg);
        float ng = 1.f - 2.f / (e2 + 1.f);
        float hnew = (1.f - zg) * ng + zg * hp;
        hp = hnew;
        hs[((long)eb * NT + t) * ND + jg] = hnew;
        unsigned short hh = f32_to_bf16(hnew);
        whg[awoff] = hh;
        wlg[awoff] = f32_to_bf16(hnew - bf16_to_f32(hh));

        grid_barrier(bar, t);
    }
}

// ---------------- CPC loss: one block per (k,l) ----------------
__global__ __launch_bounds__(256) void cp_kernel(
    const float* __restrict__ feat, const float* __restrict__ ctx,
    const int* __restrict__ perm, float* __restrict__ acc)
{
    __shared__ float cx[32][256];
    __shared__ float red2[4];

    int tid = threadIdx.x;
    int bk = blockIdx.x;
    int kk, l;
    if (bk < 511)       { kk = 1; l = bk; }
    else if (bk < 1021) { kk = 2; l = bk - 511; }
    else                { kk = 3; l = bk - 1021; }

    float dacc[5] = {0.f, 0.f, 0.f, 0.f, 0.f};
    for (int c = 0; c < 4; ++c) {
        for (int i = 0; i < 8; ++i) {
            int g = i * 256 + tid;
            int b = g >> 6, kq = g & 63;
            *(float4*)&cx[b][kq * 4] =
                *(const float4*)(ctx + (long)(b * NT + l) * ND + c * 256 + kq * 4);
        }
        __syncthreads();
        for (int oi = 0; oi < 5; ++oi) {
            int o = tid + oi * 256;
            if (o < 1056) {
                int b = o / 33, ii = o % 33;
                const float* frow = (ii < 32)
                    ? (feat + (long)(perm[(kk - 1) * 32 + ii] * NT + l) * ND)
                    : (feat + (long)(b * NT + l + kk) * ND);
                const float4* fp4 = (const float4*)(frow + c * 256);
                const float4* cp4 = (const float4*)&cx[b][0];
                float s = 0.f;
                for (int k4 = 0; k4 < 64; ++k4) {
                    float4 cf = cp4[k4];
                    float4 ff = fp4[k4];
                    s += cf.x * ff.x + cf.y * ff.y + cf.z * ff.z + cf.w * ff.w;
                }
                dacc[oi] += s;
            }
        }
        __syncthreads();
    }

    float nsum = 0.f;
    for (int oi = 0; oi < 5; ++oi) {
        int o = tid + oi * 256;
        if (o < 1056) {
            int b = o / 33, ii = o % 33;
            float x = dacc[oi];
            if (ii < 32) {
                float sn = 1.f / (1.f + expf(x));
                nsum += -logf(sn + 1e-8f);
            } else {
                float sp = 1.f / (1.f + expf(-x));
                atomicAdd(&acc[b], -logf(sp + 1e-8f));
            }
        }
    }
    #pragma unroll
    for (int m = 1; m < 64; m <<= 1) nsum += __shfl_xor(nsum, m, 64);
    if ((tid & 63) == 0) red2[tid >> 6] = nsum;
    __syncthreads();
    if (tid == 0) atomicAdd(&acc[32], red2[0] + red2[1] + red2[2] + red2[3]);
}

// ---------------- finalize ----------------
__global__ void finalize_kernel(const float* __restrict__ acc, float* __restrict__ out) {
    int b = threadIdx.x;
    if (b < 32) {
        float cp = (acc[b] + 0.25f * acc[32] * (1.0f / 1024.0f)) * (1.0f / 1527.0f);
        float vq = 1.25f * acc[33] * (1.0f / 16777216.0f);
        out[b] = cp + vq;
    }
}

// ---------------- launch ----------------
extern "C" void kernel_launch(void* const* d_in, const int* in_sizes, int n_in,
                              void* d_out, int out_size, void* d_ws, size_t ws_size,
                              hipStream_t stream)
{
    const float* feat   = (const float*)d_in[0];
    const float* cb     = (const float*)d_in[1];
    const float* W_ih   = (const float*)d_in[2];
    const float* W_hh   = (const float*)d_in[3];
    const float* b_ih   = (const float*)d_in[4];
    const float* b_hh   = (const float*)d_in[5];
    const float* W_proj = (const float*)d_in[6];
    const float* b_proj = (const float*)d_in[7];
    const int*   nperm  = (const int*)d_in[8];

    float* outq    = (float*)d_out;
    float* outidx  = outq + 16777216;
    float* outloss = outq + 16793600;

    char* ws = (char*)d_ws;
    float*          hs   = (float*)(ws);                        //  67,108,864 B
    float*          ctx  = (float*)(ws + 67108864);             //  67,108,864 B
    unsigned short* Whi  = (unsigned short*)(ws + 134217728);   //   6,291,456 B
    unsigned short* Wlo  = (unsigned short*)(ws + 140509184);   //   6,291,456 B
    float*          GIcb = (float*)(ws + 146800640);            //   3,145,728 B
    int*            idxi = (int*)(ws + 149946368);              //      65,536 B
    float*          acc  = (float*)(ws + 150011904);            //  256 B acc
    int*            bar  = (int*)(ws + 150012160);              //  256 B barrier
    unsigned short* hA   = (unsigned short*)(ws + 150012416);   //  262,144 B h frag bufs

    // zero acc, barrier, and hA buffer 0 (t=0 reads zeros) in one memset
    hipMemsetAsync(acc, 0, 512 + 131072, stream);
    prep_w<<<12288, 256, 0, stream>>>(W_hh, Whi, Wlo);
    quantize_kernel<<<2048, 256, 0, stream>>>(feat, cb, outq, outidx, idxi, acc);
    // GIcb = codebook @ W_ih^T + b_ih  (256x3072, K=1024)
    gemm_nt<<<dim3(24, 2), 256, 0, stream>>>(cb, W_ih, b_ih, GIcb, NG, ND);
    // persistent GRU: one launch, 512 in-kernel steps
    gru_persist<<<GRU_BLOCKS, 256, 0, stream>>>(hs, Whi, Wlo, GIcb, idxi, b_hh, hA, bar);
    // context_proj = hs @ W_proj^T + b_proj
    gemm_nt<<<dim3(8, 128), 256, 0, stream>>>(hs, W_proj, b_proj, ctx, ND, ND);
    cp_kernel<<<1530, 256, 0, stream>>>(feat, ctx, nperm, acc);
    finalize_kernel<<<1, 64, 0, stream>>>(acc, outloss);
}

// Round 6
// 6722.649 us; speedup vs baseline: 2.3458x; 2.3458x over previous
//
#include <hip/hip_runtime.h>
#include <stdint.h>

// Problem constants (fixed by reference): B=32, T=512, d=1024, Kcb=256
#define NB    32
#define NT    512
#define ND    1024
#define NG    3072      // 3*d
#define NROW  16384     // B*T
#define KCB   256
#define GRU_BLOCKS 128

typedef float  f32x4 __attribute__((ext_vector_type(4)));
typedef short  s16x8 __attribute__((ext_vector_type(8)));

// ---------------- bf16 helpers (hi/lo split precision) ----------------
__device__ __forceinline__ unsigned short f32_to_bf16(float x) {
    union { float f; unsigned int u; } v; v.f = x;
    unsigned int u = v.u;
    return (unsigned short)((u + 0x7FFFu + ((u >> 16) & 1u)) >> 16);
}
__device__ __forceinline__ float bf16_to_f32(unsigned short h) {
    union { float f; unsigned int u; } v; v.u = ((unsigned int)h) << 16; return v.f;
}

// ---------------- W_hh -> bf16 hi/lo split (once per launch) ----------------
__global__ __launch_bounds__(256) void prep_w(const float* __restrict__ W,
                                              unsigned short* __restrict__ Whi,
                                              unsigned short* __restrict__ Wlo) {
    int i = blockIdx.x * 256 + threadIdx.x;   // grid sized exactly: 3072*1024/256
    float w = W[i];
    unsigned short hi = f32_to_bf16(w);
    float rem = w - bf16_to_f32(hi);
    Whi[i] = hi;
    Wlo[i] = f32_to_bf16(rem);
}

// ---------------- quantize: fp64 scores, argmin, copy row, SSD ----------------
__global__ __launch_bounds__(256) void quantize_kernel(
    const float* __restrict__ feat, const float* __restrict__ cb,
    float* __restrict__ out_q, float* __restrict__ out_idx,
    int* __restrict__ idxi, float* __restrict__ acc)
{
    __shared__ float  fr[8][1024];     // 32 KB
    __shared__ double wsco[4];
    __shared__ int    wid[4];
    __shared__ int    winner;
    __shared__ float  sp[4];

    int tid = threadIdx.x;
    int r0  = blockIdx.x * 8;

    for (int i = 0; i < 8; ++i) {
        int g   = i * 256 + tid;
        int row = g >> 8;
        int kq  = g & 255;
        float4 v = ((const float4*)(feat + (long)(r0 + row) * ND))[kq];
        ((float4*)&fr[row][0])[kq] = v;
    }
    __syncthreads();

    double dot[8];
    #pragma unroll
    for (int r = 0; r < 8; ++r) dot[r] = 0.0;
    double cc = 0.0;
    const float4* cbrow = (const float4*)(cb + (long)tid * ND);
    for (int k4 = 0; k4 < 256; ++k4) {
        float4 c = cbrow[k4];
        cc += (double)c.x * (double)c.x + (double)c.y * (double)c.y
            + (double)c.z * (double)c.z + (double)c.w * (double)c.w;
        #pragma unroll
        for (int r = 0; r < 8; ++r) {
            float4 f = ((const float4*)&fr[r][0])[k4];
            dot[r] += (double)(f.x * c.x) + (double)(f.y * c.y)
                    + (double)(f.z * c.z) + (double)(f.w * c.w);
        }
    }

    float ssd_thread = 0.f;
    for (int r = 0; r < 8; ++r) {
        double s = cc - 2.0 * dot[r];
        int idx = tid;
        #pragma unroll
        for (int m = 1; m < 64; m <<= 1) {
            double s2 = __shfl_xor(s, m, 64);
            int    i2 = __shfl_xor(idx, m, 64);
            if (s2 < s || (s2 == s && i2 < idx)) { s = s2; idx = i2; }
        }
        int w = tid >> 6;
        if ((tid & 63) == 0) { wsco[w] = s; wid[w] = idx; }
        __syncthreads();
        if (tid == 0) {
            double bs = wsco[0]; int bi = wid[0];
            for (int w2 = 1; w2 < 4; ++w2)
                if (wsco[w2] < bs || (wsco[w2] == bs && wid[w2] < bi)) { bs = wsco[w2]; bi = wid[w2]; }
            winner = bi;
            out_idx[r0 + r] = (float)bi;
            idxi[r0 + r]    = bi;
        }
        __syncthreads();
        int win = winner;
        float4 q = ((const float4*)(cb + (long)win * ND))[tid];
        ((float4*)(out_q + (long)(r0 + r) * ND))[tid] = q;
        float4 f = ((const float4*)&fr[r][0])[tid];
        float dx = f.x - q.x, dy = f.y - q.y, dz = f.z - q.z, dw = f.w - q.w;
        ssd_thread += dx * dx + dy * dy + dz * dz + dw * dw;
        __syncthreads();
    }

    #pragma unroll
    for (int m = 1; m < 64; m <<= 1) ssd_thread += __shfl_xor(ssd_thread, m, 64);
    if ((tid & 63) == 0) sp[tid >> 6] = ssd_thread;
    __syncthreads();
    if (tid == 0) atomicAdd(&acc[33], sp[0] + sp[1] + sp[2] + sp[3]);
}

// ---------------- fp32 tiled GEMM: C[M,N] = A[M,K] * W[N,K]^T + bias[N] ----------------
__global__ __launch_bounds__(256) void gemm_nt(
    const float* __restrict__ A, const float* __restrict__ W,
    const float* __restrict__ bias, float* __restrict__ C, int N, int K)
{
    __shared__ float As[16][132];
    __shared__ float Bs[16][132];
    int tid = threadIdx.x;
    int m0 = blockIdx.y * 128;
    int n0 = blockIdx.x * 128;
    int tx = tid & 15, ty = tid >> 4;

    float accum[8][8];
    #pragma unroll
    for (int i = 0; i < 8; ++i)
        #pragma unroll
        for (int j = 0; j < 8; ++j) accum[i][j] = 0.f;

    for (int k0 = 0; k0 < K; k0 += 16) {
        #pragma unroll
        for (int i = 0; i < 2; ++i) {
            int f   = tid + i * 256;
            int row = f >> 2;
            int kq  = f & 3;
            float4 a = *(const float4*)(A + (long)(m0 + row) * K + k0 + kq * 4);
            As[kq * 4 + 0][row] = a.x; As[kq * 4 + 1][row] = a.y;
            As[kq * 4 + 2][row] = a.z; As[kq * 4 + 3][row] = a.w;
            float4 b = *(const float4*)(W + (long)(n0 + row) * K + k0 + kq * 4);
            Bs[kq * 4 + 0][row] = b.x; Bs[kq * 4 + 1][row] = b.y;
            Bs[kq * 4 + 2][row] = b.z; Bs[kq * 4 + 3][row] = b.w;
        }
        __syncthreads();
        #pragma unroll
        for (int kk = 0; kk < 16; ++kk) {
            float4 a01 = *(const float4*)&As[kk][ty * 8];
            float4 a23 = *(const float4*)&As[kk][ty * 8 + 4];
            float4 b01 = *(const float4*)&Bs[kk][tx * 8];
            float4 b23 = *(const float4*)&Bs[kk][tx * 8 + 4];
            float av[8] = {a01.x, a01.y, a01.z, a01.w, a23.x, a23.y, a23.z, a23.w};
            float bv[8] = {b01.x, b01.y, b01.z, b01.w, b23.x, b23.y, b23.z, b23.w};
            #pragma unroll
            for (int i = 0; i < 8; ++i)
                #pragma unroll
                for (int j = 0; j < 8; ++j) accum[i][j] += av[i] * bv[j];
        }
        __syncthreads();
    }
    #pragma unroll
    for (int i = 0; i < 8; ++i) {
        float* crow = C + (long)(m0 + ty * 8 + i) * N + n0 + tx * 8;
        const float* brow = bias + n0 + tx * 8;
        float4 o0, o1;
        o0.x = accum[i][0] + brow[0]; o0.y = accum[i][1] + brow[1];
        o0.z = accum[i][2] + brow[2]; o0.w = accum[i][3] + brow[3];
        o1.x = accum[i][4] + brow[4]; o1.y = accum[i][5] + brow[5];
        o1.z = accum[i][6] + brow[6]; o1.w = accum[i][7] + brow[7];
        *(float4*)(crow)     = o0;
        *(float4*)(crow + 4) = o1;
    }
}

// ---------------- persistent GRU v3: fence-free LLC exchange + slot barrier ----------------
// 128 blocks x 256 thr (4 waves), each block owns 8 j-cols.
// W-hi pinned in LDS, W-lo pinned in regs (loaded once, stays cached-hot: no fences ever).
// h handed between steps as PACKED (bf16hi<<16)|bf16lo dwords in A-fragment order via
// relaxed agent-scope atomics (sc0/sc1 -> LLC, bypassing L1/L2: no stale-cache risk,
// so no __threadfence invalidations). Barrier: per-block slot store + poll-all.
__global__ __launch_bounds__(256, 1) void gru_persist(
    float* hs,
    const unsigned short* __restrict__ Whi, const unsigned short* __restrict__ Wlo,
    const float* __restrict__ GIcb, const int* __restrict__ idxi,
    const float* __restrict__ b_hh,
    unsigned int* hA,     // [2 buf][32 kk][2 mt][8 j][64 lane] packed dwords
    int* slots)           // [128] per-block completed-step epochs
{
    __shared__ unsigned short whi[3][32][8][32];   // 48 KB: W-hi in B-frag layout
    __shared__ float red[4][32][25];               // 12.8 KB: k-split partials

    int tid  = threadIdx.x;
    int lane = tid & 63;
    int w    = tid >> 6;
    int bid  = blockIdx.x;
    int jb   = bid * 8;
    int q    = lane >> 4;
    int n7   = lane & 7;

    // ---- stage W-hi slice into LDS, once (24 rows x 1024 = 3072 ushort8 -> 12 iters) ----
    for (int it = 0; it < 12; ++it) {
        int u8 = it * 256 + tid;
        int e  = u8 * 8;
        int r24 = e >> 10;
        int k   = e & 1023;
        int g = r24 >> 3, r = r24 & 7;
        s16x8 v = *(const s16x8*)(Whi + (long)((g << 10) + jb + r) * 1024 + k);
        *(s16x8*)&whi[g][k >> 5][r][k & 31] = v;
    }

    // ---- pin W-lo fragments in registers (wave w covers k in [w*256, w*256+256)) ----
    s16x8 wlof[8][3];
    #pragma unroll
    for (int kl = 0; kl < 8; ++kl)
        #pragma unroll
        for (int g = 0; g < 3; ++g) {
            int kg = w * 256 + kl * 32 + q * 8;
            wlof[kl][g] = *(const s16x8*)(Wlo + (long)((g << 10) + jb + n7) * 1024 + kg);
        }
    __syncthreads();

    // ---- epilogue constants: thread -> one output (b=eb, col jg) ----
    int eb  = tid >> 3;                    // batch 0..31
    int ejl = tid & 7;                     // j-local 0..7
    int jg  = jb + ejl;
    int emt = eb >> 4, erow = eb & 15;
    int eq  = erow >> 2, eer = erow & 3;
    int esidx = eq * 8 + ejl;
    float bhr = b_hh[jg], bhz = b_hh[ND + jg], bhn = b_hh[2 * ND + jg];
    // packed-hA write slot: kk=jg>>5, q'=(jg>>3)&3, j'=jg&7, lane'=q'*16+(eb&15)
    int akk = jg >> 5, aqp = (jg >> 3) & 3, ajp = jg & 7;
    int alane = aqp * 16 + (eb & 15);
    int awoff = ((akk * 2 + emt) * 8 + ajp) * 64 + alane;
    float hp = 0.f;                        // h_prev carried in-register

    #pragma unroll 1
    for (int t = 0; t < NT; ++t) {
        // prefetch gate inputs (barrier-independent, cached reads)
        int cidx = idxi[eb * NT + t];
        const float* gib = GIcb + (long)cidx * NG;
        float gi0 = gib[jg], gi1 = gib[ND + jg], gi2 = gib[2 * ND + jg];

        // wait for all 128 blocks to have completed step t-1 (slot >= t)
        if (w == 0 && t > 0) {
            bool ok;
            do {
                int s1 = __hip_atomic_load(slots + lane,      __ATOMIC_RELAXED, __HIP_MEMORY_SCOPE_AGENT);
                int s2 = __hip_atomic_load(slots + 64 + lane, __ATOMIC_RELAXED, __HIP_MEMORY_SCOPE_AGENT);
                ok = (__all((s1 >= t) && (s2 >= t)) != 0);
                if (!ok) __builtin_amdgcn_s_sleep(1);
            } while (!ok);
        }
        __syncthreads();

        unsigned int* rA = hA + ((t & 1) << 15);         // 32768 dwords per buffer
        unsigned int* wA = hA + (((t + 1) & 1) << 15);

        f32x4 acc[2][3];
        #pragma unroll
        for (int mt = 0; mt < 2; ++mt)
            #pragma unroll
            for (int g = 0; g < 3; ++g) acc[mt][g] = (f32x4){0.f, 0.f, 0.f, 0.f};

        #pragma unroll
        for (int kl = 0; kl < 8; ++kl) {
            int kk = w * 8 + kl;
            // load packed A-fragments: lane-contiguous dwords (perfectly coalesced)
            unsigned int u0[8], u1[8];
            #pragma unroll
            for (int j = 0; j < 8; ++j) {
                u0[j] = __hip_atomic_load(rA + ((kk * 2 + 0) * 8 + j) * 64 + lane,
                                          __ATOMIC_RELAXED, __HIP_MEMORY_SCOPE_AGENT);
                u1[j] = __hip_atomic_load(rA + ((kk * 2 + 1) * 8 + j) * 64 + lane,
                                          __ATOMIC_RELAXED, __HIP_MEMORY_SCOPE_AGENT);
            }
            union Fr { s16x8 v; unsigned short e[8]; };
            Fr ah0, al0, ah1, al1;
            #pragma unroll
            for (int j = 0; j < 8; ++j) {
                ah0.e[j] = (unsigned short)(u0[j] >> 16);
                al0.e[j] = (unsigned short)(u0[j] & 0xFFFFu);
                ah1.e[j] = (unsigned short)(u1[j] >> 16);
                al1.e[j] = (unsigned short)(u1[j] & 0xFFFFu);
            }
            #pragma unroll
            for (int g = 0; g < 3; ++g) {
                s16x8 bh = *(const s16x8*)&whi[g][kk][n7][q * 8];
                s16x8 bl = wlof[kl][g];
                acc[0][g] = __builtin_amdgcn_mfma_f32_16x16x32_bf16(ah0.v, bh, acc[0][g], 0, 0, 0);
                acc[0][g] = __builtin_amdgcn_mfma_f32_16x16x32_bf16(al0.v, bh, acc[0][g], 0, 0, 0);
                acc[0][g] = __builtin_amdgcn_mfma_f32_16x16x32_bf16(ah0.v, bl, acc[0][g], 0, 0, 0);
                acc[1][g] = __builtin_amdgcn_mfma_f32_16x16x32_bf16(ah1.v, bh, acc[1][g], 0, 0, 0);
                acc[1][g] = __builtin_amdgcn_mfma_f32_16x16x32_bf16(al1.v, bh, acc[1][g], 0, 0, 0);
                acc[1][g] = __builtin_amdgcn_mfma_f32_16x16x32_bf16(ah1.v, bl, acc[1][g], 0, 0, 0);
            }
        }

        // k-split partials (only valid j lanes, n<8 within each 16-col group)
        if ((lane & 15) < 8) {
            int sidx = q * 8 + (lane & 15);
            #pragma unroll
            for (int mt = 0; mt < 2; ++mt)
                #pragma unroll
                for (int g = 0; g < 3; ++g)
                    #pragma unroll
                    for (int r = 0; r < 4; ++r)
                        red[w][sidx][(mt * 3 + g) * 4 + r] = acc[mt][g][r];
        }
        __syncthreads();

        // epilogue: 1 output per thread
        float g0 = 0.f, g1 = 0.f, g2 = 0.f;
        #pragma unroll
        for (int ww = 0; ww < 4; ++ww) {
            g0 += red[ww][esidx][(emt * 3 + 0) * 4 + eer];
            g1 += red[ww][esidx][(emt * 3 + 1) * 4 + eer];
            g2 += red[ww][esidx][(emt * 3 + 2) * 4 + eer];
        }
        float xr = gi0 + g0 + bhr;
        float xz = gi1 + g1 + bhz;
        float rg = 1.f / (1.f + __expf(-xr));
        float zg = 1.f / (1.f + __expf(-xz));
        float narg = gi2 + rg * (g2 + bhn);
        float e2 = __expf(2.f * narg);
        float ng = 1.f - 2.f / (e2 + 1.f);
        float hnew = (1.f - zg) * ng + zg * hp;
        hp = hnew;
        hs[((long)eb * NT + t) * ND + jg] = hnew;
        unsigned short hh = f32_to_bf16(hnew);
        unsigned short hl = f32_to_bf16(hnew - bf16_to_f32(hh));
        __hip_atomic_store(wA + awoff, ((unsigned int)hh << 16) | (unsigned int)hl,
                           __ATOMIC_RELAXED, __HIP_MEMORY_SCOPE_AGENT);
        __syncthreads();                    // all threads' hA stores drained (vmcnt 0)
        if (tid == 0)
            __hip_atomic_store(slots + bid, t + 1, __ATOMIC_RELEASE, __HIP_MEMORY_SCOPE_AGENT);
    }
}

// ---------------- CPC loss: one block per (k,l) ----------------
__global__ __launch_bounds__(256) void cp_kernel(
    const float* __restrict__ feat, const float* __restrict__ ctx,
    const int* __restrict__ perm, float* __restrict__ acc)
{
    __shared__ float cx[32][256];
    __shared__ float red2[4];

    int tid = threadIdx.x;
    int bk = blockIdx.x;
    int kk, l;
    if (bk < 511)       { kk = 1; l = bk; }
    else if (bk < 1021) { kk = 2; l = bk - 511; }
    else                { kk = 3; l = bk - 1021; }

    float dacc[5] = {0.f, 0.f, 0.f, 0.f, 0.f};
    for (int c = 0; c < 4; ++c) {
        for (int i = 0; i < 8; ++i) {
            int g = i * 256 + tid;
            int b = g >> 6, kq = g & 63;
            *(float4*)&cx[b][kq * 4] =
                *(const float4*)(ctx + (long)(b * NT + l) * ND + c * 256 + kq * 4);
        }
        __syncthreads();
        for (int oi = 0; oi < 5; ++oi) {
            int o = tid + oi * 256;
            if (o < 1056) {
                int b = o / 33, ii = o % 33;
                const float* frow = (ii < 32)
                    ? (feat + (long)(perm[(kk - 1) * 32 + ii] * NT + l) * ND)
                    : (feat + (long)(b * NT + l + kk) * ND);
                const float4* fp4 = (const float4*)(frow + c * 256);
                const float4* cp4 = (const float4*)&cx[b][0];
                float s = 0.f;
                for (int k4 = 0; k4 < 64; ++k4) {
                    float4 cf = cp4[k4];
                    float4 ff = fp4[k4];
                    s += cf.x * ff.x + cf.y * ff.y + cf.z * ff.z + cf.w * ff.w;
                }
                dacc[oi] += s;
            }
        }
        __syncthreads();
    }

    float nsum = 0.f;
    for (int oi = 0; oi < 5; ++oi) {
        int o = tid + oi * 256;
        if (o < 1056) {
            int b = o / 33, ii = o % 33;
            float x = dacc[oi];
            if (ii < 32) {
                float sn = 1.f / (1.f + expf(x));
                nsum += -logf(sn + 1e-8f);
            } else {
                float sp = 1.f / (1.f + expf(-x));
                atomicAdd(&acc[b], -logf(sp + 1e-8f));
            }
        }
    }
    #pragma unroll
    for (int m = 1; m < 64; m <<= 1) nsum += __shfl_xor(nsum, m, 64);
    if ((tid & 63) == 0) red2[tid >> 6] = nsum;
    __syncthreads();
    if (tid == 0) atomicAdd(&acc[32], red2[0] + red2[1] + red2[2] + red2[3]);
}

// ---------------- finalize ----------------
__global__ void finalize_kernel(const float* __restrict__ acc, float* __restrict__ out) {
    int b = threadIdx.x;
    if (b < 32) {
        float cp = (acc[b] + 0.25f * acc[32] * (1.0f / 1024.0f)) * (1.0f / 1527.0f);
        float vq = 1.25f * acc[33] * (1.0f / 16777216.0f);
        out[b] = cp + vq;
    }
}

// ---------------- launch ----------------
extern "C" void kernel_launch(void* const* d_in, const int* in_sizes, int n_in,
                              void* d_out, int out_size, void* d_ws, size_t ws_size,
                              hipStream_t stream)
{
    const float* feat   = (const float*)d_in[0];
    const float* cb     = (const float*)d_in[1];
    const float* W_ih   = (const float*)d_in[2];
    const float* W_hh   = (const float*)d_in[3];
    const float* b_ih   = (const float*)d_in[4];
    const float* b_hh   = (const float*)d_in[5];
    const float* W_proj = (const float*)d_in[6];
    const float* b_proj = (const float*)d_in[7];
    const int*   nperm  = (const int*)d_in[8];

    float* outq    = (float*)d_out;
    float* outidx  = outq + 16777216;
    float* outloss = outq + 16793600;

    char* ws = (char*)d_ws;
    float*          hs   = (float*)(ws);                        //  67,108,864 B
    float*          ctx  = (float*)(ws + 67108864);             //  67,108,864 B
    unsigned short* Whi  = (unsigned short*)(ws + 134217728);   //   6,291,456 B
    unsigned short* Wlo  = (unsigned short*)(ws + 140509184);   //   6,291,456 B
    float*          GIcb = (float*)(ws + 146800640);            //   3,145,728 B
    int*            idxi = (int*)(ws + 149946368);              //      65,536 B
    float*          acc  = (float*)(ws + 150011904);            //  256 B acc
    int*            slots= (int*)(ws + 150012160);              //  512 B barrier slots
    unsigned int*   hA   = (unsigned int*)(ws + 150012672);     //  262,144 B packed h bufs

    // zero acc (256) + slots (512) + hA buffer 0 (131072): one contiguous memset
    hipMemsetAsync(acc, 0, 256 + 512 + 131072, stream);
    prep_w<<<12288, 256, 0, stream>>>(W_hh, Whi, Wlo);
    quantize_kernel<<<2048, 256, 0, stream>>>(feat, cb, outq, outidx, idxi, acc);
    // GIcb = codebook @ W_ih^T + b_ih  (256x3072, K=1024)
    gemm_nt<<<dim3(24, 2), 256, 0, stream>>>(cb, W_ih, b_ih, GIcb, NG, ND);
    // persistent GRU: one launch, 512 in-kernel steps
    gru_persist<<<GRU_BLOCKS, 256, 0, stream>>>(hs, Whi, Wlo, GIcb, idxi, b_hh, hA, slots);
    // context_proj = hs @ W_proj^T + b_proj
    gemm_nt<<<dim3(8, 128), 256, 0, stream>>>(hs, W_proj, b_proj, ctx, ND, ND);
    cp_kernel<<<1530, 256, 0, stream>>>(feat, ctx, nperm, acc);
    finalize_kernel<<<1, 64, 0, stream>>>(acc, outloss);
}

// Round 7
// 6530.782 us; speedup vs baseline: 2.4147x; 1.0294x over previous
//
#include <hip/hip_runtime.h>
#include <stdint.h>

// Problem constants (fixed by reference): B=32, T=512, d=1024, Kcb=256
#define NB    32
#define NT    512
#define ND    1024
#define NG    3072      // 3*d
#define NROW  16384     // B*T
#define KCB   256
#define GRU_BLOCKS 128

typedef float  f32x4 __attribute__((ext_vector_type(4)));
typedef short  s16x8 __attribute__((ext_vector_type(8)));

// ---------------- bf16 helpers (hi/lo split precision) ----------------
__device__ __forceinline__ unsigned short f32_to_bf16(float x) {
    union { float f; unsigned int u; } v; v.f = x;
    unsigned int u = v.u;
    return (unsigned short)((u + 0x7FFFu + ((u >> 16) & 1u)) >> 16);
}
__device__ __forceinline__ float bf16_to_f32(unsigned short h) {
    union { float f; unsigned int u; } v; v.u = ((unsigned int)h) << 16; return v.f;
}

// LLC-coherent (L1/L2-bypassing) 16B load / 2B store — cross-XCD fresh without fences.
__device__ __forceinline__ s16x8 llc_load16(const unsigned short* p) {
    s16x8 r;
    asm volatile("global_load_dwordx4 %0, %1, off sc0 sc1" : "=v"(r) : "v"(p) : "memory");
    return r;
}
__device__ __forceinline__ void llc_store2(unsigned short* p, unsigned int v) {
    asm volatile("global_store_short %0, %1, off sc0 sc1" :: "v"(p), "v"(v) : "memory");
}

// ---------------- W_hh -> bf16 hi/lo split (once per launch) ----------------
__global__ __launch_bounds__(256) void prep_w(const float* __restrict__ W,
                                              unsigned short* __restrict__ Whi,
                                              unsigned short* __restrict__ Wlo) {
    int i = blockIdx.x * 256 + threadIdx.x;   // grid sized exactly: 3072*1024/256
    float w = W[i];
    unsigned short hi = f32_to_bf16(w);
    float rem = w - bf16_to_f32(hi);
    Whi[i] = hi;
    Wlo[i] = f32_to_bf16(rem);
}

// ---------------- quantize: fp64 scores, argmin, copy row, SSD ----------------
__global__ __launch_bounds__(256) void quantize_kernel(
    const float* __restrict__ feat, const float* __restrict__ cb,
    float* __restrict__ out_q, float* __restrict__ out_idx,
    int* __restrict__ idxi, float* __restrict__ acc)
{
    __shared__ float  fr[8][1024];     // 32 KB
    __shared__ double wsco[4];
    __shared__ int    wid[4];
    __shared__ int    winner;
    __shared__ float  sp[4];

    int tid = threadIdx.x;
    int r0  = blockIdx.x * 8;

    for (int i = 0; i < 8; ++i) {
        int g   = i * 256 + tid;
        int row = g >> 8;
        int kq  = g & 255;
        float4 v = ((const float4*)(feat + (long)(r0 + row) * ND))[kq];
        ((float4*)&fr[row][0])[kq] = v;
    }
    __syncthreads();

    double dot[8];
    #pragma unroll
    for (int r = 0; r < 8; ++r) dot[r] = 0.0;
    double cc = 0.0;
    const float4* cbrow = (const float4*)(cb + (long)tid * ND);
    for (int k4 = 0; k4 < 256; ++k4) {
        float4 c = cbrow[k4];
        cc += (double)c.x * (double)c.x + (double)c.y * (double)c.y
            + (double)c.z * (double)c.z + (double)c.w * (double)c.w;
        #pragma unroll
        for (int r = 0; r < 8; ++r) {
            float4 f = ((const float4*)&fr[r][0])[k4];
            dot[r] += (double)(f.x * c.x) + (double)(f.y * c.y)
                    + (double)(f.z * c.z) + (double)(f.w * c.w);
        }
    }

    float ssd_thread = 0.f;
    for (int r = 0; r < 8; ++r) {
        double s = cc - 2.0 * dot[r];
        int idx = tid;
        #pragma unroll
        for (int m = 1; m < 64; m <<= 1) {
            double s2 = __shfl_xor(s, m, 64);
            int    i2 = __shfl_xor(idx, m, 64);
            if (s2 < s || (s2 == s && i2 < idx)) { s = s2; idx = i2; }
        }
        int w = tid >> 6;
        if ((tid & 63) == 0) { wsco[w] = s; wid[w] = idx; }
        __syncthreads();
        if (tid == 0) {
            double bs = wsco[0]; int bi = wid[0];
            for (int w2 = 1; w2 < 4; ++w2)
                if (wsco[w2] < bs || (wsco[w2] == bs && wid[w2] < bi)) { bs = wsco[w2]; bi = wid[w2]; }
            winner = bi;
            out_idx[r0 + r] = (float)bi;
            idxi[r0 + r]    = bi;
        }
        __syncthreads();
        int win = winner;
        float4 q = ((const float4*)(cb + (long)win * ND))[tid];
        ((float4*)(out_q + (long)(r0 + r) * ND))[tid] = q;
        float4 f = ((const float4*)&fr[r][0])[tid];
        float dx = f.x - q.x, dy = f.y - q.y, dz = f.z - q.z, dw = f.w - q.w;
        ssd_thread += dx * dx + dy * dy + dz * dz + dw * dw;
        __syncthreads();
    }

    #pragma unroll
    for (int m = 1; m < 64; m <<= 1) ssd_thread += __shfl_xor(ssd_thread, m, 64);
    if ((tid & 63) == 0) sp[tid >> 6] = ssd_thread;
    __syncthreads();
    if (tid == 0) atomicAdd(&acc[33], sp[0] + sp[1] + sp[2] + sp[3]);
}

// ---------------- fp32 tiled GEMM: C[M,N] = A[M,K] * W[N,K]^T + bias[N] ----------------
__global__ __launch_bounds__(256) void gemm_nt(
    const float* __restrict__ A, const float* __restrict__ W,
    const float* __restrict__ bias, float* __restrict__ C, int N, int K)
{
    __shared__ float As[16][132];
    __shared__ float Bs[16][132];
    int tid = threadIdx.x;
    int m0 = blockIdx.y * 128;
    int n0 = blockIdx.x * 128;
    int tx = tid & 15, ty = tid >> 4;

    float accum[8][8];
    #pragma unroll
    for (int i = 0; i < 8; ++i)
        #pragma unroll
        for (int j = 0; j < 8; ++j) accum[i][j] = 0.f;

    for (int k0 = 0; k0 < K; k0 += 16) {
        #pragma unroll
        for (int i = 0; i < 2; ++i) {
            int f   = tid + i * 256;
            int row = f >> 2;
            int kq  = f & 3;
            float4 a = *(const float4*)(A + (long)(m0 + row) * K + k0 + kq * 4);
            As[kq * 4 + 0][row] = a.x; As[kq * 4 + 1][row] = a.y;
            As[kq * 4 + 2][row] = a.z; As[kq * 4 + 3][row] = a.w;
            float4 b = *(const float4*)(W + (long)(n0 + row) * K + k0 + kq * 4);
            Bs[kq * 4 + 0][row] = b.x; Bs[kq * 4 + 1][row] = b.y;
            Bs[kq * 4 + 2][row] = b.z; Bs[kq * 4 + 3][row] = b.w;
        }
        __syncthreads();
        #pragma unroll
        for (int kk = 0; kk < 16; ++kk) {
            float4 a01 = *(const float4*)&As[kk][ty * 8];
            float4 a23 = *(const float4*)&As[kk][ty * 8 + 4];
            float4 b01 = *(const float4*)&Bs[kk][tx * 8];
            float4 b23 = *(const float4*)&Bs[kk][tx * 8 + 4];
            float av[8] = {a01.x, a01.y, a01.z, a01.w, a23.x, a23.y, a23.z, a23.w};
            float bv[8] = {b01.x, b01.y, b01.z, b01.w, b23.x, b23.y, b23.z, b23.w};
            #pragma unroll
            for (int i = 0; i < 8; ++i)
                #pragma unroll
                for (int j = 0; j < 8; ++j) accum[i][j] += av[i] * bv[j];
        }
        __syncthreads();
    }
    #pragma unroll
    for (int i = 0; i < 8; ++i) {
        float* crow = C + (long)(m0 + ty * 8 + i) * N + n0 + tx * 8;
        const float* brow = bias + n0 + tx * 8;
        float4 o0, o1;
        o0.x = accum[i][0] + brow[0]; o0.y = accum[i][1] + brow[1];
        o0.z = accum[i][2] + brow[2]; o0.w = accum[i][3] + brow[3];
        o1.x = accum[i][4] + brow[4]; o1.y = accum[i][5] + brow[5];
        o1.z = accum[i][6] + brow[6]; o1.w = accum[i][7] + brow[7];
        *(float4*)(crow)     = o0;
        *(float4*)(crow + 4) = o1;
    }
}

// ---------------- persistent GRU v4: wide LLC loads, all in flight ----------------
// 128 blocks x 256 thr (4 waves), each block owns 8 j-cols.
// W-hi pinned in LDS, W-lo pinned in regs. h handed between steps as bf16 hi/lo
// ushorts in A-fragment layout via sc0|sc1 (LLC-coherent) accesses: 16B vector
// loads, ALL 32 issued before a single waitcnt -> one LLC latency per step.
// Barrier: per-block slot store + all-waves poll (no post-poll syncthreads).
__global__ __launch_bounds__(256, 1) void gru_persist(
    float* hs,
    const unsigned short* __restrict__ Whi, const unsigned short* __restrict__ Wlo,
    const float* __restrict__ GIcb, const int* __restrict__ idxi,
    const float* __restrict__ b_hh,
    unsigned short* hA,   // [2 buf][hi/lo][32 kk][2 mt][64 lane][8] ushorts (64KB/part)
    int* slots)           // [128] per-block completed-step epochs
{
    __shared__ unsigned short whi[3][32][8][32];   // 48 KB: W-hi in B-frag layout
    __shared__ float red[4][32][25];               // 12.8 KB: k-split partials

    int tid  = threadIdx.x;
    int lane = tid & 63;
    int w    = tid >> 6;
    int bid  = blockIdx.x;
    int jb   = bid * 8;
    int q    = lane >> 4;
    int n7   = lane & 7;

    // ---- stage W-hi slice into LDS, once (24 rows x 1024 = 3072 ushort8 -> 12 iters) ----
    for (int it = 0; it < 12; ++it) {
        int u8 = it * 256 + tid;
        int e  = u8 * 8;
        int r24 = e >> 10;
        int k   = e & 1023;
        int g = r24 >> 3, r = r24 & 7;
        s16x8 v = *(const s16x8*)(Whi + (long)((g << 10) + jb + r) * 1024 + k);
        *(s16x8*)&whi[g][k >> 5][r][k & 31] = v;
    }

    // ---- pin W-lo fragments in registers (wave w covers k in [w*256, w*256+256)) ----
    s16x8 wlof[8][3];
    #pragma unroll
    for (int kl = 0; kl < 8; ++kl)
        #pragma unroll
        for (int g = 0; g < 3; ++g) {
            int kg = w * 256 + kl * 32 + q * 8;
            wlof[kl][g] = *(const s16x8*)(Wlo + (long)((g << 10) + jb + n7) * 1024 + kg);
        }
    __syncthreads();

    // ---- epilogue constants: thread -> one output (b=eb, col jg) ----
    int eb  = tid >> 3;                    // batch 0..31
    int ejl = tid & 7;                     // j-local 0..7
    int jg  = jb + ejl;
    int emt = eb >> 4, erow = eb & 15;
    int eq  = erow >> 2, eer = erow & 3;
    int esidx = eq * 8 + ejl;
    float bhr = b_hh[jg], bhz = b_hh[ND + jg], bhn = b_hh[2 * ND + jg];
    // hA write slot (A-frag layout): kk=jg>>5, q'=(jg>>3)&3, e=jg&7, lane'=q'*16+(eb&15)
    int akk = jg >> 5, aqp = (jg >> 3) & 3, aj8 = jg & 7;
    int alane = aqp * 16 + (eb & 15);
    int awoff = ((akk * 2 + emt) * 64 + alane) * 8 + aj8;
    float hp = 0.f;                        // h_prev carried in-register

    #pragma unroll 1
    for (int t = 0; t < NT; ++t) {
        // prefetch gate inputs (barrier-independent, cached reads)
        int cidx = idxi[eb * NT + t];
        const float* gib = GIcb + (long)cidx * NG;
        float gi0 = gib[jg], gi1 = gib[ND + jg], gi2 = gib[2 * ND + jg];

        // all waves poll: all 128 blocks completed step t-1 (slot >= t)
        if (t > 0) {
            bool ok;
            do {
                int s1 = __hip_atomic_load(slots + lane,      __ATOMIC_RELAXED, __HIP_MEMORY_SCOPE_AGENT);
                int s2 = __hip_atomic_load(slots + 64 + lane, __ATOMIC_RELAXED, __HIP_MEMORY_SCOPE_AGENT);
                ok = (__all((s1 >= t) && (s2 >= t)) != 0);
                if (!ok) __builtin_amdgcn_s_sleep(1);
            } while (!ok);
        }

        const unsigned short* rHi = hA + ((unsigned)(t & 1) * 2 + 0) * 32768;
        const unsigned short* rLo = rHi + 32768;
        unsigned short* wHi = hA + ((unsigned)((t + 1) & 1) * 2 + 0) * 32768;
        unsigned short* wLo = wHi + 32768;

        // ---- issue ALL 32 A-fragment loads (16B each), one waitcnt ----
        s16x8 Ah[8][2], Al[8][2];
        #pragma unroll
        for (int kl = 0; kl < 8; ++kl) {
            int kk = w * 8 + kl;
            const unsigned short* ph = rHi + (kk * 2) * 512 + lane * 8;
            const unsigned short* pl = rLo + (kk * 2) * 512 + lane * 8;
            Ah[kl][0] = llc_load16(ph);
            Ah[kl][1] = llc_load16(ph + 512);
            Al[kl][0] = llc_load16(pl);
            Al[kl][1] = llc_load16(pl + 512);
        }
        asm volatile("s_waitcnt vmcnt(0)" ::: "memory");

        f32x4 acc[2][3];
        #pragma unroll
        for (int mt = 0; mt < 2; ++mt)
            #pragma unroll
            for (int g = 0; g < 3; ++g) acc[mt][g] = (f32x4){0.f, 0.f, 0.f, 0.f};

        #pragma unroll
        for (int kl = 0; kl < 8; ++kl) {
            int kk = w * 8 + kl;
            #pragma unroll
            for (int g = 0; g < 3; ++g) {
                s16x8 bh = *(const s16x8*)&whi[g][kk][n7][q * 8];
                s16x8 bl = wlof[kl][g];
                acc[0][g] = __builtin_amdgcn_mfma_f32_16x16x32_bf16(Ah[kl][0], bh, acc[0][g], 0, 0, 0);
                acc[0][g] = __builtin_amdgcn_mfma_f32_16x16x32_bf16(Al[kl][0], bh, acc[0][g], 0, 0, 0);
                acc[0][g] = __builtin_amdgcn_mfma_f32_16x16x32_bf16(Ah[kl][0], bl, acc[0][g], 0, 0, 0);
                acc[1][g] = __builtin_amdgcn_mfma_f32_16x16x32_bf16(Ah[kl][1], bh, acc[1][g], 0, 0, 0);
                acc[1][g] = __builtin_amdgcn_mfma_f32_16x16x32_bf16(Al[kl][1], bh, acc[1][g], 0, 0, 0);
                acc[1][g] = __builtin_amdgcn_mfma_f32_16x16x32_bf16(Ah[kl][1], bl, acc[1][g], 0, 0, 0);
            }
        }

        // k-split partials (only valid j lanes)
        if ((lane & 15) < 8) {
            int sidx = q * 8 + (lane & 15);
            #pragma unroll
            for (int mt = 0; mt < 2; ++mt)
                #pragma unroll
                for (int g = 0; g < 3; ++g)
                    #pragma unroll
                    for (int r = 0; r < 4; ++r)
                        red[w][sidx][(mt * 3 + g) * 4 + r] = acc[mt][g][r];
        }
        __syncthreads();

        // epilogue: 1 output per thread
        float g0 = 0.f, g1 = 0.f, g2 = 0.f;
        #pragma unroll
        for (int ww = 0; ww < 4; ++ww) {
            g0 += red[ww][esidx][(emt * 3 + 0) * 4 + eer];
            g1 += red[ww][esidx][(emt * 3 + 1) * 4 + eer];
            g2 += red[ww][esidx][(emt * 3 + 2) * 4 + eer];
        }
        float xr = gi0 + g0 + bhr;
        float xz = gi1 + g1 + bhz;
        float rg = 1.f / (1.f + __expf(-xr));
        float zg = 1.f / (1.f + __expf(-xz));
        float narg = gi2 + rg * (g2 + bhn);
        float e2 = __expf(2.f * narg);
        float ng = 1.f - 2.f / (e2 + 1.f);
        float hnew = (1.f - zg) * ng + zg * hp;
        hp = hnew;
        hs[((long)eb * NT + t) * ND + jg] = hnew;
        unsigned short hh = f32_to_bf16(hnew);
        unsigned short hl = f32_to_bf16(hnew - bf16_to_f32(hh));
        llc_store2(wHi + awoff, (unsigned int)hh);
        llc_store2(wLo + awoff, (unsigned int)hl);
        asm volatile("s_waitcnt vmcnt(0)" ::: "memory");   // h stores drained
        __syncthreads();                                   // whole block done
        if (tid == 0)
            __hip_atomic_store(slots + bid, t + 1, __ATOMIC_RELEASE, __HIP_MEMORY_SCOPE_AGENT);
    }
}

// ---------------- CPC loss: one block per (k,l) ----------------
__global__ __launch_bounds__(256) void cp_kernel(
    const float* __restrict__ feat, const float* __restrict__ ctx,
    const int* __restrict__ perm, float* __restrict__ acc)
{
    __shared__ float cx[32][256];
    __shared__ float red2[4];

    int tid = threadIdx.x;
    int bk = blockIdx.x;
    int kk, l;
    if (bk < 511)       { kk = 1; l = bk; }
    else if (bk < 1021) { kk = 2; l = bk - 511; }
    else                { kk = 3; l = bk - 1021; }

    float dacc[5] = {0.f, 0.f, 0.f, 0.f, 0.f};
    for (int c = 0; c < 4; ++c) {
        for (int i = 0; i < 8; ++i) {
            int g = i * 256 + tid;
            int b = g >> 6, kq = g & 63;
            *(float4*)&cx[b][kq * 4] =
                *(const float4*)(ctx + (long)(b * NT + l) * ND + c * 256 + kq * 4);
        }
        __syncthreads();
        for (int oi = 0; oi < 5; ++oi) {
            int o = tid + oi * 256;
            if (o < 1056) {
                int b = o / 33, ii = o % 33;
                const float* frow = (ii < 32)
                    ? (feat + (long)(perm[(kk - 1) * 32 + ii] * NT + l) * ND)
                    : (feat + (long)(b * NT + l + kk) * ND);
                const float4* fp4 = (const float4*)(frow + c * 256);
                const float4* cp4 = (const float4*)&cx[b][0];
                float s = 0.f;
                for (int k4 = 0; k4 < 64; ++k4) {
                    float4 cf = cp4[k4];
                    float4 ff = fp4[k4];
                    s += cf.x * ff.x + cf.y * ff.y + cf.z * ff.z + cf.w * ff.w;
                }
                dacc[oi] += s;
            }
        }
        __syncthreads();
    }

    float nsum = 0.f;
    for (int oi = 0; oi < 5; ++oi) {
        int o = tid + oi * 256;
        if (o < 1056) {
            int b = o / 33, ii = o % 33;
            float x = dacc[oi];
            if (ii < 32) {
                float sn = 1.f / (1.f + expf(x));
                nsum += -logf(sn + 1e-8f);
            } else {
                float sp = 1.f / (1.f + expf(-x));
                atomicAdd(&acc[b], -logf(sp + 1e-8f));
            }
        }
    }
    #pragma unroll
    for (int m = 1; m < 64; m <<= 1) nsum += __shfl_xor(nsum, m, 64);
    if ((tid & 63) == 0) red2[tid >> 6] = nsum;
    __syncthreads();
    if (tid == 0) atomicAdd(&acc[32], red2[0] + red2[1] + red2[2] + red2[3]);
}

// ---------------- finalize ----------------
__global__ void finalize_kernel(const float* __restrict__ acc, float* __restrict__ out) {
    int b = threadIdx.x;
    if (b < 32) {
        float cp = (acc[b] + 0.25f * acc[32] * (1.0f / 1024.0f)) * (1.0f / 1527.0f);
        float vq = 1.25f * acc[33] * (1.0f / 16777216.0f);
        out[b] = cp + vq;
    }
}

// ---------------- launch ----------------
extern "C" void kernel_launch(void* const* d_in, const int* in_sizes, int n_in,
                              void* d_out, int out_size, void* d_ws, size_t ws_size,
                              hipStream_t stream)
{
    const float* feat   = (const float*)d_in[0];
    const float* cb     = (const float*)d_in[1];
    const float* W_ih   = (const float*)d_in[2];
    const float* W_hh   = (const float*)d_in[3];
    const float* b_ih   = (const float*)d_in[4];
    const float* b_hh   = (const float*)d_in[5];
    const float* W_proj = (const float*)d_in[6];
    const float* b_proj = (const float*)d_in[7];
    const int*   nperm  = (const int*)d_in[8];

    float* outq    = (float*)d_out;
    float* outidx  = outq + 16777216;
    float* outloss = outq + 16793600;

    char* ws = (char*)d_ws;
    float*          hs   = (float*)(ws);                        //  67,108,864 B
    float*          ctx  = (float*)(ws + 67108864);             //  67,108,864 B
    unsigned short* Whi  = (unsigned short*)(ws + 134217728);   //   6,291,456 B
    unsigned short* Wlo  = (unsigned short*)(ws + 140509184);   //   6,291,456 B
    float*          GIcb = (float*)(ws + 146800640);            //   3,145,728 B
    int*            idxi = (int*)(ws + 149946368);              //      65,536 B
    float*          acc  = (float*)(ws + 150011904);            //  256 B acc
    int*            slots= (int*)(ws + 150012160);              //  512 B barrier slots
    unsigned short* hA   = (unsigned short*)(ws + 150012672);   //  262,144 B h frag bufs

    // zero acc (256) + slots (512) + hA buffer 0 hi+lo (131072): one contiguous memset
    hipMemsetAsync(acc, 0, 256 + 512 + 131072, stream);
    prep_w<<<12288, 256, 0, stream>>>(W_hh, Whi, Wlo);
    quantize_kernel<<<2048, 256, 0, stream>>>(feat, cb, outq, outidx, idxi, acc);
    // GIcb = codebook @ W_ih^T + b_ih  (256x3072, K=1024)
    gemm_nt<<<dim3(24, 2), 256, 0, stream>>>(cb, W_ih, b_ih, GIcb, NG, ND);
    // persistent GRU: one launch, 512 in-kernel steps
    gru_persist<<<GRU_BLOCKS, 256, 0, stream>>>(hs, Whi, Wlo, GIcb, idxi, b_hh, hA, slots);
    // context_proj = hs @ W_proj^T + b_proj
    gemm_nt<<<dim3(8, 128), 256, 0, stream>>>(hs, W_proj, b_proj, ctx, ND, ND);
    cp_kernel<<<1530, 256, 0, stream>>>(feat, ctx, nperm, acc);
    finalize_kernel<<<1, 64, 0, stream>>>(acc, outloss);
}